// Round 1
// baseline (2163.405 us; speedup 1.0000x reference)
//
#include <hip/hip_runtime.h>
#include <math.h>

#define B_ 64
#define T_ 1024
#define D_ 768
#define A_ 128

// ---------------- tiled fp32 GEMM: C[M,N] = (tanh?)(A @ B) ----------------
// A: row-major [M,K] (TRANS_A=false) or stored [K,M] (TRANS_A=true)
// B: row-major [K,N].  Tile 128x128, K-step 32, 256 threads, 8x8 per thread.
template<bool TRANS_A, bool TANH>
__global__ __launch_bounds__(256)
void gemm_tile(const float* __restrict__ Abase, const float* __restrict__ Bbase,
               float* __restrict__ Cbase, int M, int N, int K,
               size_t sA, size_t sB, size_t sC) {
  __shared__ float AsT[32][132];   // [k][m], pad 132 to spread banks, 528B row (16B-aligned)
  __shared__ float Bs[32][128];    // [k][n]
  const int bz = blockIdx.z;
  const float* Ap = Abase + sA * bz;
  const float* Bp = Bbase + sB * bz;
  float* Cp = Cbase + sC * bz;
  const int n0 = blockIdx.x * 128;
  const int m0 = blockIdx.y * 128;
  const int tid = threadIdx.x;
  const int tx = tid & 15;
  const int ty = tid >> 4;
  float acc[8][8];
#pragma unroll
  for (int i = 0; i < 8; ++i)
#pragma unroll
    for (int j = 0; j < 8; ++j) acc[i][j] = 0.f;

  for (int k0 = 0; k0 < K; k0 += 32) {
    if (!TRANS_A) {
      // A row-major [M,K]: read float4 along k, transpose into AsT
#pragma unroll
      for (int u = 0; u < 4; ++u) {
        int idx = tid + u * 256;      // 0..1023
        int r = idx >> 3;             // 0..127 (m)
        int kq = (idx & 7) << 2;      // 0..28 (k quad)
        float4 v = *(const float4*)(Ap + (size_t)(m0 + r) * K + k0 + kq);
        AsT[kq + 0][r] = v.x;
        AsT[kq + 1][r] = v.y;
        AsT[kq + 2][r] = v.z;
        AsT[kq + 3][r] = v.w;
      }
    } else {
      // A stored [K,M]: rows are contiguous in m, copy straight in
#pragma unroll
      for (int u = 0; u < 4; ++u) {
        int idx = tid + u * 256;
        int r = idx >> 5;             // 0..31 (k)
        int cq = (idx & 31) << 2;     // 0..124 (m quad)
        float4 v = *(const float4*)(Ap + (size_t)(k0 + r) * M + m0 + cq);
        *(float4*)&AsT[r][cq] = v;
      }
    }
#pragma unroll
    for (int u = 0; u < 4; ++u) {
      int idx = tid + u * 256;
      int r = idx >> 5;               // 0..31 (k)
      int cq = (idx & 31) << 2;       // 0..124 (n quad)
      float4 v = *(const float4*)(Bp + (size_t)(k0 + r) * N + n0 + cq);
      *(float4*)&Bs[r][cq] = v;
    }
    __syncthreads();
#pragma unroll 8
    for (int kk = 0; kk < 32; ++kk) {
      float4 a0 = *(const float4*)&AsT[kk][ty * 8];
      float4 a1 = *(const float4*)&AsT[kk][ty * 8 + 4];
      float4 b0 = *(const float4*)&Bs[kk][tx * 8];
      float4 b1 = *(const float4*)&Bs[kk][tx * 8 + 4];
      float av[8] = {a0.x, a0.y, a0.z, a0.w, a1.x, a1.y, a1.z, a1.w};
      float bv[8] = {b0.x, b0.y, b0.z, b0.w, b1.x, b1.y, b1.z, b1.w};
#pragma unroll
      for (int i = 0; i < 8; ++i)
#pragma unroll
        for (int j = 0; j < 8; ++j) acc[i][j] += av[i] * bv[j];
    }
    __syncthreads();
  }
#pragma unroll
  for (int i = 0; i < 8; ++i) {
    float vout[8];
#pragma unroll
    for (int j = 0; j < 8; ++j) vout[j] = TANH ? tanhf(acc[i][j]) : acc[i][j];
    float* Cr = Cp + (size_t)(m0 + ty * 8 + i) * N + n0 + tx * 8;
    *(float4*)(Cr)     = make_float4(vout[0], vout[1], vout[2], vout[3]);
    *(float4*)(Cr + 4) = make_float4(vout[4], vout[5], vout[6], vout[7]);
  }
}

// softmax over t (axis 0 of the [T(t),T(s)] logit tile per batch), in place.
// One thread per column s; reads/writes coalesced across the wave.
__global__ __launch_bounds__(256)
void softmax_col(float* __restrict__ S) {
  const int bb = blockIdx.y;
  const int s = blockIdx.x * 256 + threadIdx.x;
  float* col = S + (size_t)bb * T_ * T_ + s;
  float m = -1e30f;
  for (int t = 0; t < T_; ++t) m = fmaxf(m, col[(size_t)t * T_]);
  float sum = 0.f;
  for (int t = 0; t < T_; ++t) {
    float e = expf(col[(size_t)t * T_] - m);
    col[(size_t)t * T_] = e;
    sum += e;
  }
  float inv = 1.0f / sum;
  for (int t = 0; t < T_; ++t) col[(size_t)t * T_] *= inv;
}

extern "C" void kernel_launch(void* const* d_in, const int* in_sizes, int n_in,
                              void* d_out, int out_size, void* d_ws, size_t ws_size,
                              hipStream_t stream) {
  const float* x  = (const float*)d_in[0];   // [B,T,D]
  const float* W1 = (const float*)d_in[1];   // [D,A]
  const float* W2 = (const float*)d_in[2];   // [A,T]
  float* out = (float*)d_out;                // [B,T,D]

  // Workspace per batch: H [T,A] + S [T,T] floats. Chunk batches to fit ws.
  const size_t perB_floats = (size_t)T_ * A_ + (size_t)T_ * T_;
  int chunk = (int)(ws_size / (perB_floats * sizeof(float)));
  if (chunk > B_) chunk = B_;
  if (chunk < 1) chunk = 1;
  float* Hbuf = (float*)d_ws;

  for (int b0 = 0; b0 < B_; b0 += chunk) {
    int nb = B_ - b0;
    if (nb > chunk) nb = chunk;
    float* Sbuf = Hbuf + (size_t)nb * T_ * A_;

    // 1) H = tanh(x @ W1): M=T, N=A, K=D
    gemm_tile<false, true><<<dim3(A_ / 128, T_ / 128, nb), 256, 0, stream>>>(
        x + (size_t)b0 * T_ * D_, W1, Hbuf, T_, A_, D_,
        (size_t)T_ * D_, 0, (size_t)T_ * A_);

    // 2) S = H @ W2: M=T(t), N=T(s), K=A
    gemm_tile<false, false><<<dim3(T_ / 128, T_ / 128, nb), 256, 0, stream>>>(
        Hbuf, W2, Sbuf, T_, T_, A_,
        (size_t)T_ * A_, 0, (size_t)T_ * T_);

    // 3) softmax over t, in place (S -> P)
    softmax_col<<<dim3(T_ / 256, nb), 256, 0, stream>>>(Sbuf);

    // 4) out[s,d] = sum_t P[t,s] * x[t,d]: A = P stored [K=t][M=s] -> TRANS_A
    gemm_tile<true, false><<<dim3(D_ / 128, T_ / 128, nb), 256, 0, stream>>>(
        Sbuf, x + (size_t)b0 * T_ * D_, out + (size_t)b0 * T_ * D_,
        T_, D_, T_,
        (size_t)T_ * T_, (size_t)T_ * D_, (size_t)T_ * D_);
  }
}

// Round 2
// 425.932 us; speedup vs baseline: 5.0792x; 5.0792x over previous
//
#include <hip/hip_runtime.h>
#include <math.h>

#define B_ 64
#define T_ 1024
#define D_ 768
#define A_ 128

typedef __attribute__((ext_vector_type(4))) float f32x4;
typedef __attribute__((ext_vector_type(8))) short s16x8;
typedef __attribute__((ext_vector_type(4))) short s16x4;

__device__ inline short f2b(float f) {
  union { float f; unsigned u; } v; v.f = f;
  unsigned r = (v.u + 0x7FFFu + ((v.u >> 16) & 1u)) >> 16;
  return (short)r;
}
__device__ inline float b2f(short s) {
  union { unsigned u; float f; } v; v.u = ((unsigned)(unsigned short)s) << 16;
  return v.f;
}

__device__ inline void gll16(const void* g, const void* lds) {
  __builtin_amdgcn_global_load_lds(
      (const __attribute__((address_space(1))) unsigned*)g,
      (__attribute__((address_space(3))) unsigned*)lds, 16, 0, 0);
}

// ---------------------------------------------------------------------------
// bf16 MFMA GEMM, m97-style: C[M,N] = A[M,K] @ Bt[N,K]^T
//   A:  bf16 [M,K] row-major, staged via global_load_lds (LDS linear)
//   Bt: bf16 [N,K] row-major (B^T layout) via global_load_lds,
//       or fp32 [N,K] (BF32=true) reg-staged with convert
//   WT: write C transposed -> Cout[n][m] (row stride M), else Cout[m][n]
//   OB16: bf16 output (packed 4-elem 8B stores), else fp32 scalar stores
// 128x128 tile, BK=64, 256 threads (4 waves, each 64x64 = 4x4 frags 16x16x32)
// ---------------------------------------------------------------------------
template<bool BF32, bool TANH_, bool WT, bool OB16>
__global__ __launch_bounds__(256, 2)
void gemm_bt(const short* __restrict__ Ab, const void* __restrict__ Bv,
             void* __restrict__ Cv, int M, int N, int K,
             long sA, long sB, long sC) {
  __shared__ __align__(16) short As[128 * 64];
  __shared__ __align__(16) short Bs[128 * 64];
  const int tid = threadIdx.x;
  const int w = tid >> 6, lane = tid & 63;
  const int n0 = blockIdx.x * 128, m0 = blockIdx.y * 128;
  const int wr = w >> 1, wc = w & 1;
  const int lr = lane & 15, lq = lane >> 4;
  const short* A = Ab + (size_t)sA * blockIdx.z;
  const short* Bb16 = nullptr; const float* Bf32 = nullptr;
  if (BF32) Bf32 = (const float*)Bv + (size_t)sB * blockIdx.z;
  else      Bb16 = (const short*)Bv + (size_t)sB * blockIdx.z;

  f32x4 acc[4][4] = {};

  const int r8 = lane >> 3, c8 = lane & 7;

  for (int k0 = 0; k0 < K; k0 += 64) {
    __syncthreads();
    // ---- stage A tile [128 m][64 k] bf16, LDS linear ----
#pragma unroll
    for (int i = 0; i < 4; ++i) {
      int chunk = w * 4 + i;                 // 0..15, 1KB LDS each
      int row = chunk * 8 + r8;              // 0..127
      gll16(A + (size_t)(m0 + row) * K + k0 + c8 * 8, As + chunk * 512);
    }
    // ---- stage Bt tile [128 n][64 k] ----
    if (!BF32) {
#pragma unroll
      for (int i = 0; i < 4; ++i) {
        int chunk = w * 4 + i;
        int row = chunk * 8 + r8;
        gll16(Bb16 + (size_t)(n0 + row) * K + k0 + c8 * 8, Bs + chunk * 512);
      }
    } else {
#pragma unroll
      for (int u = 0; u < 4; ++u) {
        int c = tid * 4 + u;                 // 0..1023 chunks of 8 bf16
        int row = c >> 3, k8 = c & 7;
        const float* gp = Bf32 + (size_t)(n0 + row) * K + k0 + k8 * 8;
        float4 f0 = *(const float4*)gp;
        float4 f1 = *(const float4*)(gp + 4);
        s16x8 p;
        p[0] = f2b(f0.x); p[1] = f2b(f0.y); p[2] = f2b(f0.z); p[3] = f2b(f0.w);
        p[4] = f2b(f1.x); p[5] = f2b(f1.y); p[6] = f2b(f1.z); p[7] = f2b(f1.w);
        *(s16x8*)&Bs[row * 64 + k8 * 8] = p;
      }
    }
    __syncthreads();
    // ---- MFMA: 2 k-substeps of 32, 4x4 frags per wave ----
#pragma unroll
    for (int kk = 0; kk < 2; ++kk) {
      s16x8 a[4], b[4];
#pragma unroll
      for (int mf = 0; mf < 4; ++mf)
        a[mf] = *(const s16x8*)&As[(wr * 64 + mf * 16 + lr) * 64 + kk * 32 + lq * 8];
#pragma unroll
      for (int nf = 0; nf < 4; ++nf)
        b[nf] = *(const s16x8*)&Bs[(wc * 64 + nf * 16 + lr) * 64 + kk * 32 + lq * 8];
#pragma unroll
      for (int mf = 0; mf < 4; ++mf)
#pragma unroll
        for (int nf = 0; nf < 4; ++nf)
          acc[mf][nf] = __builtin_amdgcn_mfma_f32_16x16x32_bf16(
              a[mf], b[nf], acc[mf][nf], 0, 0, 0);
    }
  }

  // ---- epilogue; C/D layout: col = lane&15, row = (lane>>4)*4 + q ----
  if (WT) {
    if (OB16) {
      short* C = (short*)Cv + (size_t)sC * blockIdx.z;
#pragma unroll
      for (int mf = 0; mf < 4; ++mf)
#pragma unroll
        for (int nf = 0; nf < 4; ++nf) {
          int mbase = m0 + wr * 64 + mf * 16 + lq * 4;
          int n = n0 + wc * 64 + nf * 16 + lr;
          s16x4 pk;
#pragma unroll
          for (int q = 0; q < 4; ++q) {
            float v = acc[mf][nf][q];
            if (TANH_) v = tanhf(v);
            pk[q] = f2b(v);
          }
          *(s16x4*)(C + (size_t)n * M + mbase) = pk;
        }
    } else {
      float* C = (float*)Cv + (size_t)sC * blockIdx.z;
#pragma unroll
      for (int mf = 0; mf < 4; ++mf)
#pragma unroll
        for (int nf = 0; nf < 4; ++nf) {
          int mbase = m0 + wr * 64 + mf * 16 + lq * 4;
          int n = n0 + wc * 64 + nf * 16 + lr;
#pragma unroll
          for (int q = 0; q < 4; ++q) {
            float v = acc[mf][nf][q];
            if (TANH_) v = tanhf(v);
            C[(size_t)n * M + mbase + q] = v;
          }
        }
    }
  } else {
    float* C = (float*)Cv + (size_t)sC * blockIdx.z;
#pragma unroll
    for (int mf = 0; mf < 4; ++mf)
#pragma unroll
      for (int nf = 0; nf < 4; ++nf) {
        int m = m0 + wr * 64 + mf * 16 + lq * 4;
        int n = n0 + wc * 64 + nf * 16 + lr;
#pragma unroll
        for (int q = 0; q < 4; ++q) {
          float v = acc[mf][nf][q];
          if (TANH_) v = tanhf(v);
          C[(size_t)(m + q) * N + n] = v;
        }
      }
  }
}

// ---------------------------------------------------------------------------
// transpose + fp32->bf16: src [z][R][C] fp32 -> dst [z][C][R] bf16. 64x64 tiles.
// ---------------------------------------------------------------------------
__global__ __launch_bounds__(256)
void transpose_cvt(const float* __restrict__ src, short* __restrict__ dst,
                   int R, int C) {
  __shared__ float sh[64][68];
  const int tid = threadIdx.x;
  const float* s = src + (size_t)blockIdx.z * R * C;
  short* d = dst + (size_t)blockIdx.z * R * C;
  const int r0 = blockIdx.y * 64, c0 = blockIdx.x * 64;
#pragma unroll
  for (int u = 0; u < 4; ++u) {
    int e = tid + u * 256;
    int rr = e >> 4, cc4 = (e & 15) * 4;
    *(float4*)&sh[rr][cc4] = *(const float4*)&s[(size_t)(r0 + rr) * C + c0 + cc4];
  }
  __syncthreads();
#pragma unroll
  for (int u = 0; u < 4; ++u) {
    int e = tid + u * 256;
    int dr = e >> 4, tc4 = (e & 15) * 4;
    s16x4 pk;
#pragma unroll
    for (int j = 0; j < 4; ++j) pk[j] = f2b(sh[tc4 + j][dr]);
    *(s16x4*)&d[(size_t)(c0 + dr) * R + r0 + tc4] = pk;
  }
}

// ---------------------------------------------------------------------------
// in-place row softmax on bf16 [nb][T][T]; one wave per row, 16 elems/lane
// ---------------------------------------------------------------------------
__global__ __launch_bounds__(256)
void softmax_rows(short* __restrict__ St) {
  const int w = threadIdx.x >> 6, lane = threadIdx.x & 63;
  short* rp = St + ((size_t)blockIdx.y * T_ + blockIdx.x * 4 + w) * T_;
  s16x8 v0 = *(const s16x8*)&rp[lane * 16];
  s16x8 v1 = *(const s16x8*)&rp[lane * 16 + 8];
  float f[16];
#pragma unroll
  for (int j = 0; j < 8; ++j) { f[j] = b2f(v0[j]); f[j + 8] = b2f(v1[j]); }
  float m = f[0];
#pragma unroll
  for (int j = 1; j < 16; ++j) m = fmaxf(m, f[j]);
#pragma unroll
  for (int o = 32; o; o >>= 1) m = fmaxf(m, __shfl_xor(m, o));
  float ssum = 0.f;
#pragma unroll
  for (int j = 0; j < 16; ++j) { f[j] = __expf(f[j] - m); ssum += f[j]; }
#pragma unroll
  for (int o = 32; o; o >>= 1) ssum += __shfl_xor(ssum, o);
  float inv = 1.0f / ssum;
#pragma unroll
  for (int j = 0; j < 8; ++j) { v0[j] = f2b(f[j] * inv); v1[j] = f2b(f[j + 8] * inv); }
  *(s16x8*)&rp[lane * 16] = v0;
  *(s16x8*)&rp[lane * 16 + 8] = v1;
}

extern "C" void kernel_launch(void* const* d_in, const int* in_sizes, int n_in,
                              void* d_out, int out_size, void* d_ws, size_t ws_size,
                              hipStream_t stream) {
  const float* x  = (const float*)d_in[0];   // [B,T,D]
  const float* W1 = (const float*)d_in[1];   // [D,A]
  const float* W2 = (const float*)d_in[2];   // [A,T]
  float* out = (float*)d_out;                // [B,T,D] fp32

  // ws layout (bf16/shorts): xt[B,D,T] | W1t[A,D] | W2t[T,A] | H[B,T,A] | St[nb,T,T]
  short* xt  = (short*)d_ws;
  short* W1t = xt + (size_t)B_ * D_ * T_;
  short* W2t = W1t + (size_t)A_ * D_;
  short* H   = W2t + (size_t)T_ * A_;
  short* St  = H + (size_t)B_ * T_ * A_;
  size_t fixed_bytes = (size_t)(St - xt) * sizeof(short);
  long avail = (long)ws_size - (long)fixed_bytes;
  long per_b = (long)T_ * T_ * sizeof(short);
  int chunk = (int)(avail > 0 ? avail / per_b : 0);
  if (chunk > B_) chunk = B_;
  if (chunk < 1) chunk = 1;

  // prep: transposed bf16 copies
  transpose_cvt<<<dim3(D_ / 64, T_ / 64, B_), 256, 0, stream>>>(x, xt, T_, D_);
  transpose_cvt<<<dim3(A_ / 64, D_ / 64, 1), 256, 0, stream>>>(W1, W1t, D_, A_);
  transpose_cvt<<<dim3(T_ / 64, A_ / 64, 1), 256, 0, stream>>>(W2, W2t, A_, T_);

  // G1: compute H^T = W1t @ x^T (M=A,N=T,K=D), transposed write -> H[t][a] bf16, tanh
  gemm_bt<true, true, true, true><<<dim3(T_ / 128, A_ / 128, B_), 256, 0, stream>>>(
      W1t, x, H, A_, T_, D_, 0, (long)T_ * D_, (long)T_ * A_);

  for (int b0 = 0; b0 < B_; b0 += chunk) {
    int nb = B_ - b0; if (nb > chunk) nb = chunk;
    // G2: S[t,s] = H @ W2t^T (M=T,N=T,K=A), transposed write -> St[s][t] bf16
    gemm_bt<false, false, true, true><<<dim3(T_ / 128, T_ / 128, nb), 256, 0, stream>>>(
        H + (size_t)b0 * T_ * A_, W2t, St, T_, T_, A_,
        (long)T_ * A_, 0, (long)T_ * T_);
    // softmax over t = rows of St, in place, bf16 out
    softmax_rows<<<dim3(T_ / 4, nb), 256, 0, stream>>>(St);
    // G4: out[s,d] = Pt @ xt^T (M=T,N=D,K=T), fp32 write
    gemm_bt<false, false, false, false><<<dim3(D_ / 128, T_ / 128, nb), 256, 0, stream>>>(
        St, xt + (size_t)b0 * (size_t)D_ * T_, out + (size_t)b0 * (size_t)T_ * D_,
        T_, D_, T_, (long)T_ * T_, (long)D_ * T_, (long)T_ * D_);
  }
}

// Round 3
// 381.759 us; speedup vs baseline: 5.6669x; 1.1157x over previous
//
#include <hip/hip_runtime.h>
#include <math.h>

#define B_ 64
#define T_ 1024
#define D_ 768
#define A_ 128

typedef __attribute__((ext_vector_type(4))) float f32x4;
typedef __attribute__((ext_vector_type(8))) short s16x8;
typedef __attribute__((ext_vector_type(4))) short s16x4;

__device__ inline short f2b(float f) {
  union { float f; unsigned u; } v; v.f = f;
  unsigned r = (v.u + 0x7FFFu + ((v.u >> 16) & 1u)) >> 16;
  return (short)r;
}
__device__ inline float b2f(short s) {
  union { unsigned u; float f; } v; v.u = ((unsigned)(unsigned short)s) << 16;
  return v.f;
}

__device__ inline void gll16(const void* g, const void* lds) {
  __builtin_amdgcn_global_load_lds(
      (const __attribute__((address_space(1))) unsigned*)g,
      (__attribute__((address_space(3))) unsigned*)lds, 16, 0, 0);
}

// ---------------------------------------------------------------------------
// bf16 MFMA GEMM, m97-style: C[M,N] = A[M,K] @ Bt[N,K]^T
//   A:  bf16 [M,K] row-major, staged via global_load_lds (LDS linear)
//   Bt: bf16 [N,K] row-major (B^T layout) via global_load_lds,
//       or fp32 [N,K] (BF32=true) reg-staged with convert
//   WT: write C transposed -> Cout[n][m] (row stride M), else Cout[m][n]
//   OB16: bf16 output (packed 4-elem 8B stores), else fp32 scalar stores
// 128x128 tile, BK=64, 256 threads (4 waves, each 64x64 = 4x4 frags 16x16x32)
// Launched 1D; XCD batch-affinity swizzle (m204 bijective): XCD k owns a
// contiguous chunk of block-ids -> per-XCD L2 holds ~1 batch's panels.
// ---------------------------------------------------------------------------
template<bool BF32, bool TANH_, bool WT, bool OB16>
__global__ __launch_bounds__(256, 2)
void gemm_bt(const short* __restrict__ Ab, const void* __restrict__ Bv,
             void* __restrict__ Cv, int M, int N, int K,
             long sA, long sB, long sC, int gx, int gy) {
  __shared__ __align__(16) short As[128 * 64];
  __shared__ __align__(16) short Bs[128 * 64];
  // ---- bijective XCD swizzle ----
  unsigned nwg = gridDim.x;
  unsigned L = blockIdx.x;
  unsigned xcd = L & 7u, base = L >> 3;
  unsigned q = nwg >> 3, r = nwg & 7u;
  unsigned id = (xcd < r ? xcd * (q + 1) : r * (q + 1) + (xcd - r) * q) + base;
  const int gxy = gx * gy;
  const int bz = id / gxy;
  const int rem = id - bz * gxy;
  const int by = rem / gx;
  const int bx = rem - by * gx;

  const int tid = threadIdx.x;
  const int w = tid >> 6, lane = tid & 63;
  const int n0 = bx * 128, m0 = by * 128;
  const int wr = w >> 1, wc = w & 1;
  const int lr = lane & 15, lq = lane >> 4;
  const short* A = Ab + (size_t)sA * bz;
  const short* Bb16 = nullptr; const float* Bf32 = nullptr;
  if (BF32) Bf32 = (const float*)Bv + (size_t)sB * bz;
  else      Bb16 = (const short*)Bv + (size_t)sB * bz;

  f32x4 acc[4][4] = {};

  const int r8 = lane >> 3, c8 = lane & 7;

  for (int k0 = 0; k0 < K; k0 += 64) {
    __syncthreads();
    // ---- stage A tile [128 m][64 k] bf16, LDS linear ----
#pragma unroll
    for (int i = 0; i < 4; ++i) {
      int chunk = w * 4 + i;                 // 0..15, 1KB LDS each
      int row = chunk * 8 + r8;              // 0..127
      gll16(A + (size_t)(m0 + row) * K + k0 + c8 * 8, As + chunk * 512);
    }
    // ---- stage Bt tile [128 n][64 k] ----
    if (!BF32) {
#pragma unroll
      for (int i = 0; i < 4; ++i) {
        int chunk = w * 4 + i;
        int row = chunk * 8 + r8;
        gll16(Bb16 + (size_t)(n0 + row) * K + k0 + c8 * 8, Bs + chunk * 512);
      }
    } else {
#pragma unroll
      for (int u = 0; u < 4; ++u) {
        int c = tid * 4 + u;                 // 0..1023 chunks of 8 bf16
        int row = c >> 3, k8 = c & 7;
        const float* gp = Bf32 + (size_t)(n0 + row) * K + k0 + k8 * 8;
        float4 f0 = *(const float4*)gp;
        float4 f1 = *(const float4*)(gp + 4);
        s16x8 p;
        p[0] = f2b(f0.x); p[1] = f2b(f0.y); p[2] = f2b(f0.z); p[3] = f2b(f0.w);
        p[4] = f2b(f1.x); p[5] = f2b(f1.y); p[6] = f2b(f1.z); p[7] = f2b(f1.w);
        *(s16x8*)&Bs[row * 64 + k8 * 8] = p;
      }
    }
    __syncthreads();
    // ---- MFMA: 2 k-substeps of 32, 4x4 frags per wave ----
#pragma unroll
    for (int kk = 0; kk < 2; ++kk) {
      s16x8 a[4], b[4];
#pragma unroll
      for (int mf = 0; mf < 4; ++mf)
        a[mf] = *(const s16x8*)&As[(wr * 64 + mf * 16 + lr) * 64 + kk * 32 + lq * 8];
#pragma unroll
      for (int nf = 0; nf < 4; ++nf)
        b[nf] = *(const s16x8*)&Bs[(wc * 64 + nf * 16 + lr) * 64 + kk * 32 + lq * 8];
#pragma unroll
      for (int mf = 0; mf < 4; ++mf)
#pragma unroll
        for (int nf = 0; nf < 4; ++nf)
          acc[mf][nf] = __builtin_amdgcn_mfma_f32_16x16x32_bf16(
              a[mf], b[nf], acc[mf][nf], 0, 0, 0);
    }
  }

  // ---- epilogue; C/D layout: col = lane&15, row = (lane>>4)*4 + q ----
  if (WT) {
    if (OB16) {
      short* C = (short*)Cv + (size_t)sC * bz;
#pragma unroll
      for (int mf = 0; mf < 4; ++mf)
#pragma unroll
        for (int nf = 0; nf < 4; ++nf) {
          int mbase = m0 + wr * 64 + mf * 16 + lq * 4;
          int n = n0 + wc * 64 + nf * 16 + lr;
          s16x4 pk;
#pragma unroll
          for (int qq = 0; qq < 4; ++qq) {
            float v = acc[mf][nf][qq];
            if (TANH_) v = tanhf(v);
            pk[qq] = f2b(v);
          }
          *(s16x4*)(C + (size_t)n * M + mbase) = pk;
        }
    } else {
      float* C = (float*)Cv + (size_t)sC * bz;
#pragma unroll
      for (int mf = 0; mf < 4; ++mf)
#pragma unroll
        for (int nf = 0; nf < 4; ++nf) {
          int mbase = m0 + wr * 64 + mf * 16 + lq * 4;
          int n = n0 + wc * 64 + nf * 16 + lr;
#pragma unroll
          for (int qq = 0; qq < 4; ++qq) {
            float v = acc[mf][nf][qq];
            if (TANH_) v = tanhf(v);
            C[(size_t)n * M + mbase + qq] = v;
          }
        }
    }
  } else {
    float* C = (float*)Cv + (size_t)sC * bz;
#pragma unroll
    for (int mf = 0; mf < 4; ++mf)
#pragma unroll
      for (int nf = 0; nf < 4; ++nf) {
        int m = m0 + wr * 64 + mf * 16 + lq * 4;
        int n = n0 + wc * 64 + nf * 16 + lr;
#pragma unroll
        for (int qq = 0; qq < 4; ++qq) {
          float v = acc[mf][nf][qq];
          if (TANH_) v = tanhf(v);
          C[(size_t)(m + qq) * N + n] = v;
        }
      }
  }
}

// ---------------------------------------------------------------------------
// transpose + fp32->bf16: src [z][R][C] fp32 -> dst [z][C][R] bf16. 64x64 tiles.
// ---------------------------------------------------------------------------
__global__ __launch_bounds__(256)
void transpose_cvt(const float* __restrict__ src, short* __restrict__ dst,
                   int R, int C) {
  __shared__ float sh[64][68];
  const int tid = threadIdx.x;
  const float* s = src + (size_t)blockIdx.z * R * C;
  short* d = dst + (size_t)blockIdx.z * R * C;
  const int r0 = blockIdx.y * 64, c0 = blockIdx.x * 64;
#pragma unroll
  for (int u = 0; u < 4; ++u) {
    int e = tid + u * 256;
    int rr = e >> 4, cc4 = (e & 15) * 4;
    *(float4*)&sh[rr][cc4] = *(const float4*)&s[(size_t)(r0 + rr) * C + c0 + cc4];
  }
  __syncthreads();
#pragma unroll
  for (int u = 0; u < 4; ++u) {
    int e = tid + u * 256;
    int dr = e >> 4, tc4 = (e & 15) * 4;
    s16x4 pk;
#pragma unroll
    for (int j = 0; j < 4; ++j) pk[j] = f2b(sh[tc4 + j][dr]);
    *(s16x4*)&d[(size_t)(c0 + dr) * R + r0 + tc4] = pk;
  }
}

// ---------------------------------------------------------------------------
// in-place row softmax on bf16 [nb][T][T]; one wave per row, 16 elems/lane
// ---------------------------------------------------------------------------
__global__ __launch_bounds__(256)
void softmax_rows(short* __restrict__ St) {
  const int w = threadIdx.x >> 6, lane = threadIdx.x & 63;
  short* rp = St + ((size_t)blockIdx.y * T_ + blockIdx.x * 4 + w) * T_;
  s16x8 v0 = *(const s16x8*)&rp[lane * 16];
  s16x8 v1 = *(const s16x8*)&rp[lane * 16 + 8];
  float f[16];
#pragma unroll
  for (int j = 0; j < 8; ++j) { f[j] = b2f(v0[j]); f[j + 8] = b2f(v1[j]); }
  float m = f[0];
#pragma unroll
  for (int j = 1; j < 16; ++j) m = fmaxf(m, f[j]);
#pragma unroll
  for (int o = 32; o; o >>= 1) m = fmaxf(m, __shfl_xor(m, o));
  float ssum = 0.f;
#pragma unroll
  for (int j = 0; j < 16; ++j) { f[j] = __expf(f[j] - m); ssum += f[j]; }
#pragma unroll
  for (int o = 32; o; o >>= 1) ssum += __shfl_xor(ssum, o);
  float inv = 1.0f / ssum;
#pragma unroll
  for (int j = 0; j < 8; ++j) { v0[j] = f2b(f[j] * inv); v1[j] = f2b(f[j + 8] * inv); }
  *(s16x8*)&rp[lane * 16] = v0;
  *(s16x8*)&rp[lane * 16 + 8] = v1;
}

extern "C" void kernel_launch(void* const* d_in, const int* in_sizes, int n_in,
                              void* d_out, int out_size, void* d_ws, size_t ws_size,
                              hipStream_t stream) {
  const float* x  = (const float*)d_in[0];   // [B,T,D]
  const float* W1 = (const float*)d_in[1];   // [D,A]
  const float* W2 = (const float*)d_in[2];   // [A,T]
  float* out = (float*)d_out;                // [B,T,D] fp32

  // ws layout (bf16/shorts): xt[B,D,T] | W1t[A,D] | W2t[T,A] | H[B,T,A] | St[nb,T,T]
  short* xt  = (short*)d_ws;
  short* W1t = xt + (size_t)B_ * D_ * T_;
  short* W2t = W1t + (size_t)A_ * D_;
  short* H   = W2t + (size_t)T_ * A_;
  short* St  = H + (size_t)B_ * T_ * A_;
  size_t fixed_bytes = (size_t)(St - xt) * sizeof(short);
  long avail = (long)ws_size - (long)fixed_bytes;
  long per_b = (long)T_ * T_ * sizeof(short);
  int chunk = (int)(avail > 0 ? avail / per_b : 0);
  if (chunk > B_) chunk = B_;
  if (chunk < 1) chunk = 1;

  // prep: transposed bf16 copies
  transpose_cvt<<<dim3(D_ / 64, T_ / 64, B_), 256, 0, stream>>>(x, xt, T_, D_);
  transpose_cvt<<<dim3(A_ / 64, D_ / 64, 1), 256, 0, stream>>>(W1, W1t, D_, A_);
  transpose_cvt<<<dim3(T_ / 64, A_ / 64, 1), 256, 0, stream>>>(W2, W2t, A_, T_);

  // G1: H^T = W1t @ x^T (M=A,N=T,K=D), transposed write -> H[t][a] bf16, tanh
  gemm_bt<true, true, true, true><<<(T_ / 128) * (A_ / 128) * B_, 256, 0, stream>>>(
      W1t, x, H, A_, T_, D_, 0, (long)T_ * D_, (long)T_ * A_,
      T_ / 128, A_ / 128);

  for (int b0 = 0; b0 < B_; b0 += chunk) {
    int nb = B_ - b0; if (nb > chunk) nb = chunk;
    // G2: S[t,s] = H @ W2t^T (M=T,N=T,K=A), transposed write -> St[s][t] bf16
    gemm_bt<false, false, true, true><<<(T_ / 128) * (T_ / 128) * nb, 256, 0, stream>>>(
        H + (size_t)b0 * T_ * A_, W2t, St, T_, T_, A_,
        (long)T_ * A_, 0, (long)T_ * T_,
        T_ / 128, T_ / 128);
    // softmax over t = rows of St, in place, bf16 out
    softmax_rows<<<dim3(T_ / 4, nb), 256, 0, stream>>>(St);
    // G4: out[s,d] = Pt @ xt^T (M=T,N=D,K=T), fp32 write
    gemm_bt<false, false, false, false><<<(D_ / 128) * (T_ / 128) * nb, 256, 0, stream>>>(
        St, xt + (size_t)b0 * (size_t)D_ * T_, out + (size_t)b0 * (size_t)T_ * D_,
        T_, D_, T_, (long)T_ * T_, (long)D_ * T_, (long)T_ * D_,
        D_ / 128, T_ / 128);
  }
}